// Round 12
// baseline (209.724 us; speedup 1.0000x reference)
//
#include <hip/hip_runtime.h>
#include <stdint.h>

// TimestepPermutationQuantizer — PASSED r8-r11 with absmax 0.0. The
// arithmetic chain below is BIT-EXACT vs the harness golden — DO NOT CHANGE:
//   scale = fmaxf(mx-mn, 1e-5f) * (1.0f/15.0f)   // XLA const-div rewrite
//   base  = clip(rintf(-mn/scale), 0, 15)        // IEEE f32 div, half-even
//   q     = clip(rintf(v/scale) + base, 0, 15)   // IEEE f32 div
//   out   = (q - base) * scale
// Partition P1: group g members = {gat[g*128+k]}, gat = d_in[1];
// channel c's group = asn[c]>>7, asn = d_in[2].
//
// Perf log: r8 125.5 -> r9 118.7 (DMA+dbuf) -> r10 127.7 (shfl sb: DS ops up,
// regressed) -> r11 104.7 (P2 re-geometry 48->8 shfl; partial-drain barrier).
// r12 "reg-row": rows stage через registers; LDS only holds ONE 16KB rowbuf
// for the P2 gather; P3 quantizes from registers (no LDS re-read); next-row
// global loads issue at iteration top (T14 issue-early) and ds_write lands
// after P3 behind a gather-complete barrier. NO vmcnt-draining barriers at
// all (2x lgkmcnt-only raw barriers per row). BLOCK=256 + 16.6KB LDS ->
// 8 blocks/CU (finer barrier domains, 2x independent streams vs r11).

constexpr int C     = 4096;
constexpr int GS    = 128;
constexpr int NG    = C / GS;          // 32 groups
constexpr int BLOCK = 256;             // 4 waves
constexpr int VECS  = C / 4 / BLOCK;   // 4 float4 per thread
constexpr int NSG   = BLOCK / 16;      // 16 subgroups of 16 lanes
constexpr int GPS   = NG / NSG;        // 2 groups per subgroup

__global__ __launch_bounds__(BLOCK, 8) void tpq_kernel(
    const float* __restrict__ x,
    const int*   __restrict__ gat,   // d_in[1]: group g = {gat[g*128+k]}
    const int*   __restrict__ asn,   // d_in[2]: channel c -> pos asn[c]
    float*       __restrict__ out,
    int rows)
{
    __shared__ float  rowbuf[C];
    __shared__ float2 sb[NG];

    const int tid  = threadIdx.x;
    const int wave = tid >> 6;
    const int lane = tid & 63;
    const int sg   = wave * 4 + (lane >> 4);  // subgroup 0..15
    const int sl   = lane & 15;               // lane in subgroup

    float4* rw4 = reinterpret_cast<float4*>(rowbuf);

    // ---- row-invariant: packed 5-bit group ids (4 per u32) ----
    uint32_t gpack[VECS];
    #pragma unroll
    for (int i = 0; i < VECS; ++i) {
        const int4 a = reinterpret_cast<const int4*>(asn)[tid + i * BLOCK];
        gpack[i] = (uint32_t)(a.x >> 7)        | ((uint32_t)(a.y >> 7) << 8)
                 | ((uint32_t)(a.z >> 7) << 16) | ((uint32_t)(a.w >> 7) << 24);
    }

    int r = blockIdx.x;
    float4 va[VECS], vb[VECS];

    // ---- prologue: load row r into regs, stage to LDS ----
    {
        const float4* x4 = reinterpret_cast<const float4*>(x + (size_t)r * C);
        #pragma unroll
        for (int i = 0; i < VECS; ++i) va[i] = x4[tid + i * BLOCK];
        #pragma unroll
        for (int i = 0; i < VECS; ++i) rw4[tid + i * BLOCK] = va[i];
        __syncthreads();
    }

    float4* vcur = va;
    float4* vnxt = vb;

    while (true) {
        const int  rn = r + gridDim.x;
        const bool hn = rn < rows;

        // ---- issue next-row loads NOW (land during P2+P3) ----
        if (hn) {
            const float4* nx4 = reinterpret_cast<const float4*>(x + (size_t)rn * C);
            #pragma unroll
            for (int i = 0; i < VECS; ++i) vnxt[i] = nx4[tid + i * BLOCK];
        }

        // ---- P2: 16 lanes/group, 8 elems/lane, 2 groups per subgroup ----
        #pragma unroll
        for (int gi = 0; gi < GPS; ++gi) {
            const int g = sg * GPS + gi;
            const int4* gp4 = reinterpret_cast<const int4*>(gat + g * GS + sl * 8);
            const int4 ia = gp4[0], ib = gp4[1];
            const float x0 = rowbuf[ia.x], x1 = rowbuf[ia.y];
            const float x2 = rowbuf[ia.z], x3 = rowbuf[ia.w];
            const float x4v = rowbuf[ib.x], x5 = rowbuf[ib.y];
            const float x6 = rowbuf[ib.z], x7 = rowbuf[ib.w];
            float mx = fmaxf(fmaxf(fmaxf(x0, x1), fmaxf(x2, x3)),
                             fmaxf(fmaxf(x4v, x5), fmaxf(x6, x7)));
            float mn = fminf(fminf(fminf(x0, x1), fminf(x2, x3)),
                             fminf(fminf(x4v, x5), fminf(x6, x7)));
            #pragma unroll
            for (int off = 8; off; off >>= 1) {   // stays in 16-lane subgroup
                mx = fmaxf(mx, __shfl_xor(mx, off));
                mn = fminf(mn, __shfl_xor(mn, off));
            }
            if (sl == 0) {
                const float s = fmaxf(mx - mn, 1e-5f) * (1.0f / 15.0f);
                const float b = fminf(fmaxf(rintf(-mn / s), 0.0f), 15.0f);
                sb[g] = make_float2(s, b);
            }
        }

        // ---- raw barrier: sb visible; all gathers of row r done ----
        asm volatile("s_waitcnt lgkmcnt(0)\n\ts_barrier" ::: "memory");

        // ---- P3: quantize FROM REGISTERS, coalesced store ----
        float4* or4 = reinterpret_cast<float4*>(out + (size_t)r * C);
        #pragma unroll
        for (int i = 0; i < VECS; ++i) {
            const float4   v  = vcur[i];
            const uint32_t gp = gpack[i];
            float4 o;
            { const float2 p = sb[gp & 31u];
              o.x = (fminf(fmaxf(rintf(v.x / p.x) + p.y, 0.0f), 15.0f) - p.y) * p.x; }
            { const float2 p = sb[(gp >> 8) & 31u];
              o.y = (fminf(fmaxf(rintf(v.y / p.x) + p.y, 0.0f), 15.0f) - p.y) * p.x; }
            { const float2 p = sb[(gp >> 16) & 31u];
              o.z = (fminf(fmaxf(rintf(v.z / p.x) + p.y, 0.0f), 15.0f) - p.y) * p.x; }
            { const float2 p = sb[(gp >> 24) & 31u];
              o.w = (fminf(fmaxf(rintf(v.w / p.x) + p.y, 0.0f), 15.0f) - p.y) * p.x; }
            or4[tid + i * BLOCK] = o;
        }

        if (!hn) break;

        // ---- stage next row to LDS (gathers done; rowbuf free) ----
        #pragma unroll
        for (int i = 0; i < VECS; ++i) rw4[tid + i * BLOCK] = vnxt[i];
        // raw barrier: rowbuf(rn) visible; sb of row r consumed by all waves
        asm volatile("s_waitcnt lgkmcnt(0)\n\ts_barrier" ::: "memory");

        r = rn;
        float4* t = vcur; vcur = vnxt; vnxt = t;
    }
}

extern "C" void kernel_launch(void* const* d_in, const int* in_sizes, int n_in,
                              void* d_out, int out_size, void* d_ws, size_t ws_size,
                              hipStream_t stream) {
    const float* x   = (const float*)d_in[0];
    const int*   gat = (const int*)d_in[1];   // perm (gather) — P1 partition
    const int*   asn = (const int*)d_in[2];   // inverse perm (assignment)
    float* out = (float*)d_out;

    const int rows = in_sizes[0] / C;            // 16384
    const int nblk = rows < 2048 ? rows : 2048;  // 8 rows/block grid-stride

    tpq_kernel<<<nblk, BLOCK, 0, stream>>>(x, gat, asn, out, rows);
}

// Round 13
// 135.002 us; speedup vs baseline: 1.5535x; 1.5535x over previous
//
#include <hip/hip_runtime.h>
#include <stdint.h>

// TimestepPermutationQuantizer — PASSED r8-r12 with absmax 0.0. The
// arithmetic chain below is BIT-EXACT vs the harness golden — DO NOT CHANGE:
//   scale = fmaxf(mx-mn, 1e-5f) * (1.0f/15.0f)   // XLA const-div rewrite
//   base  = clip(rintf(-mn/scale), 0, 15)        // IEEE f32 div, half-even
//   q     = clip(rintf(v/scale) + base, 0, 15)   // IEEE f32 div
//   out   = (q - base) * scale
// Partition P1: group g members = {gat[g*128+k]}, gat = d_in[1].
//
// Perf log: r8 125.5 -> r9 118.7 -> r10 127.7 (shfl sb lookup: DS ops up) ->
// r11 104.7 (P2 re-geometry, partial-drain barriers) -> r12 209.7 (BLOCK=256
// reg-row: launch_bounds(256,8) VGPR cap 64 -> va/vb SPILLED, WRITE_SIZE
// 262->526MB scratch traffic).
// r13 "quant-at-gather": after the butterfly every lane holds mx/mn, so each
// lane quantizes the 8 values it GATHERED (group is lane-uniform -> NO per-
// element (s,b) lookup, sb[] table deleted, asn[] input unused). Results
// scatter to outbuf; P3 is a pure linear outbuf->global copy. Next row
// prefetches into 8 VGPRs (BLOCK=512 -> VECS=2) and is ds_written to the
// single rowbuf after the gather-complete barrier. 2 lgkmcnt-only raw
// barriers/row; NO barrier-wide vmcnt drains (prefetch waits are per-wave).
// LDS 32KB -> 4 blocks/CU, 32 waves/CU.

constexpr int C     = 4096;
constexpr int GS    = 128;
constexpr int NG    = C / GS;          // 32 groups
constexpr int BLOCK = 512;             // 8 waves; 32 subgroups of 16 lanes
constexpr int VECS  = C / 4 / BLOCK;   // 2 float4 per thread

__global__ __launch_bounds__(BLOCK, 8) void tpq_kernel(
    const float* __restrict__ x,
    const int*   __restrict__ gat,   // d_in[1]: group g = {gat[g*128+k]}
    float*       __restrict__ out,
    int rows)
{
    __shared__ float rowbuf[C];
    __shared__ float outbuf[C];

    const int tid = threadIdx.x;
    const int sg  = tid >> 4;          // subgroup == group id (32 of each)
    const int sl  = tid & 15;          // lane within 16-lane subgroup

    float4* rw4 = reinterpret_cast<float4*>(rowbuf);
    float4* ob4 = reinterpret_cast<float4*>(outbuf);

    // ---- row-invariant: this lane's 8 permuted channel indices ----
    int pidx[8];
    {
        const int4* g4 = reinterpret_cast<const int4*>(gat + sg * GS + sl * 8);
        const int4 a = g4[0], b = g4[1];
        pidx[0] = a.x; pidx[1] = a.y; pidx[2] = a.z; pidx[3] = a.w;
        pidx[4] = b.x; pidx[5] = b.y; pidx[6] = b.z; pidx[7] = b.w;
    }

    int r = blockIdx.x;
    float4 vnxt[VECS];

    // ---- prologue: stage row r into rowbuf via regs ----
    {
        const float4* x4 = reinterpret_cast<const float4*>(x + (size_t)r * C);
        #pragma unroll
        for (int i = 0; i < VECS; ++i) vnxt[i] = x4[tid + i * BLOCK];
        #pragma unroll
        for (int i = 0; i < VECS; ++i) rw4[tid + i * BLOCK] = vnxt[i];
        __syncthreads();
    }

    while (true) {
        const int  rn = r + gridDim.x;
        const bool hn = rn < rows;

        // ---- issue next-row coalesced loads (land during P2) ----
        if (hn) {
            const float4* nx4 = reinterpret_cast<const float4*>(x + (size_t)rn * C);
            #pragma unroll
            for (int i = 0; i < VECS; ++i) vnxt[i] = nx4[tid + i * BLOCK];
        }

        // ---- P2: gather 8, butterfly min/max, quantize in-reg, scatter ----
        float gv[8];
        #pragma unroll
        for (int k = 0; k < 8; ++k) gv[k] = rowbuf[pidx[k]];

        float mx = fmaxf(fmaxf(fmaxf(gv[0], gv[1]), fmaxf(gv[2], gv[3])),
                         fmaxf(fmaxf(gv[4], gv[5]), fmaxf(gv[6], gv[7])));
        float mn = fminf(fminf(fminf(gv[0], gv[1]), fminf(gv[2], gv[3])),
                         fminf(fminf(gv[4], gv[5]), fminf(gv[6], gv[7])));
        #pragma unroll
        for (int off = 8; off; off >>= 1) {   // stays in 16-lane subgroup
            mx = fmaxf(mx, __shfl_xor(mx, off));
            mn = fminf(mn, __shfl_xor(mn, off));
        }
        // every lane now holds the full-group mx/mn (bitwise identical):
        const float s = fmaxf(mx - mn, 1e-5f) * (1.0f / 15.0f);
        const float b = fminf(fmaxf(rintf(-mn / s), 0.0f), 15.0f);
        #pragma unroll
        for (int k = 0; k < 8; ++k) {
            const float q = fminf(fmaxf(rintf(gv[k] / s) + b, 0.0f), 15.0f);
            outbuf[pidx[k]] = (q - b) * s;
        }

        // ---- raw barrier: outbuf complete; rowbuf fully consumed ----
        asm volatile("s_waitcnt lgkmcnt(0)\n\ts_barrier" ::: "memory");

        // ---- P3: linear outbuf -> global copy; restage rowbuf with rn ----
        float4 o[VECS];
        #pragma unroll
        for (int i = 0; i < VECS; ++i) o[i] = ob4[tid + i * BLOCK];
        if (hn) {
            // per-wave vmcnt wait on vnxt (compiler-inserted), no barrier
            #pragma unroll
            for (int i = 0; i < VECS; ++i) rw4[tid + i * BLOCK] = vnxt[i];
        }
        float4* or4 = reinterpret_cast<float4*>(out + (size_t)r * C);
        #pragma unroll
        for (int i = 0; i < VECS; ++i) or4[tid + i * BLOCK] = o[i];

        if (!hn) break;

        // ---- raw barrier: rowbuf(rn) staged; outbuf reads done ----
        asm volatile("s_waitcnt lgkmcnt(0)\n\ts_barrier" ::: "memory");
        r = rn;
    }
}

extern "C" void kernel_launch(void* const* d_in, const int* in_sizes, int n_in,
                              void* d_out, int out_size, void* d_ws, size_t ws_size,
                              hipStream_t stream) {
    const float* x   = (const float*)d_in[0];
    const int*   gat = (const int*)d_in[1];   // perm (gather) — P1 partition
    // d_in[2] (assignment array) no longer needed: quant happens at gather,
    // where the group is lane-uniform.
    float* out = (float*)d_out;

    const int rows = in_sizes[0] / C;            // 16384
    const int nblk = rows < 2048 ? rows : 2048;  // 8 rows/block grid-stride

    tpq_kernel<<<nblk, BLOCK, 0, stream>>>(x, gat, out, rows);
}

// Round 14
// 103.091 us; speedup vs baseline: 2.0344x; 1.3095x over previous
//
#include <hip/hip_runtime.h>
#include <stdint.h>

// TimestepPermutationQuantizer — PASSED r8-r13 with absmax 0.0. The
// arithmetic chain below is BIT-EXACT vs the harness golden — DO NOT CHANGE:
//   scale = fmaxf(mx-mn, 1e-5f) * (1.0f/15.0f)   // XLA const-div rewrite
//   base  = clip(rintf(-mn/scale), 0, 15)        // IEEE f32 div, half-even
//   q     = clip(rintf(v/scale) + base, 0, 15)   // IEEE f32 div
//   out   = (q - base) * scale
// Partition P1: group g members = {gat[g*128+k]}, gat = d_in[1];
// channel c's group = asn[c]>>7, asn = d_in[2].
//
// Perf log: r8 125.5 -> r9 118.7 (DMA+dbuf) -> r10 127.7 (shfl sb: +16 DS ops,
// regressed) -> r11 104.7 (P2 re-geometry, partial-drain barriers) ->
// r12 209.7 (VGPR spill: reg-arrays + tight launch bound -> scratch) ->
// r13 135.0 (quant-at-gather: +8 scattered ds_writes + outbuf reads).
// MODEL: DS pipe is per-CU and co-dominant with HBM (~60us of DS traffic at
// r11's op mix). Every DS op removed ~= 2us.
// r14 = r11 + two DS diets:
//  (1) butterfly via DPP (quad_perm 0xB1/0x4E, row_half_mirror, row_mirror):
//      VALU-pipe cross-lane, removes 8 DS shfl/thread-row. fmax/fmin are
//      exactly associative -> bit-identical reduction.
//  (2) sb table at stride-3 floats ({3g,3g+1}): gcd(3,32)=1 spreads the
//      32-entry table over all banks (float2 layout used only even banks ->
//      4-way conflicts); adjacent pair merges into one ds_read2_b32.

constexpr int C     = 4096;
constexpr int GS    = 128;
constexpr int NG    = C / GS;          // 32 groups
constexpr int BLOCK = 512;             // 8 waves
constexpr int WAVES = BLOCK / 64;
constexpr int GPW   = NG / WAVES;      // 4 groups per wave (concurrent)
constexpr int VECS  = C / 4 / BLOCK;   // 2 float4 per thread in P3

typedef const __attribute__((address_space(1))) uint32_t glb_u32;
typedef __attribute__((address_space(3))) uint32_t lds_u32;

__device__ __forceinline__ void stage_row(const float* __restrict__ src,
                                          float* dst, int wave, int lane) {
    // DMA one 16 KiB row: per wave 2 chunks of 64 lanes x 16 B.
    // LDS dest = wave-uniform base + lane*16 (HW rule); global src per-lane.
    #pragma unroll
    for (int i = 0; i < 2; ++i) {
        const float* g = src + i * 2048 + wave * 256 + lane * 4;
        float*       l = dst + i * 2048 + wave * 256;
        __builtin_amdgcn_global_load_lds((glb_u32*)(uintptr_t)g,
                                         (lds_u32*)(uintptr_t)l, 16, 0, 0);
    }
}

template<int CTRL>
__device__ __forceinline__ float dpp_bcast(float x) {
    // VALU-pipe cross-lane move (DPP), no DS usage.
    return __int_as_float(__builtin_amdgcn_update_dpp(
        0, __float_as_int(x), CTRL, 0xF, 0xF, true));
}

__global__ __launch_bounds__(BLOCK, 8) void tpq_kernel(
    const float* __restrict__ x,
    const int*   __restrict__ gat,   // d_in[1]: group g = {gat[g*128+k]}
    const int*   __restrict__ asn,   // d_in[2]: channel c -> pos asn[c]
    float*       __restrict__ out,
    int rows)
{
    __shared__ float rowbuf[2][C];
    __shared__ float sbx[2][NG * 3];   // (s,b) at {3g, 3g+1}, stride-3 floats

    const int tid  = threadIdx.x;
    const int wave = tid >> 6;
    const int lane = tid & 63;
    const int sub  = lane >> 4;        // which of 4 groups in this wave
    const int sl   = lane & 15;        // lane within 16-lane subgroup
    const int g    = wave * GPW + sub; // this lane's P2 group

    // ---- row-invariant preloads (once per block) ----
    int pidx[8];                       // 8 of this group's permuted channels
    {
        const int4* g4 = reinterpret_cast<const int4*>(gat + g * GS + sl * 8);
        const int4 a = g4[0], b = g4[1];
        pidx[0] = a.x; pidx[1] = a.y; pidx[2] = a.z; pidx[3] = a.w;
        pidx[4] = b.x; pidx[5] = b.y; pidx[6] = b.z; pidx[7] = b.w;
    }
    uint32_t gpack[VECS];              // 4x 5-bit group ids per u32
    #pragma unroll
    for (int i = 0; i < VECS; ++i) {
        const int4 a = reinterpret_cast<const int4*>(asn)[tid + i * BLOCK];
        gpack[i] = (uint32_t)(a.x >> 7)        | ((uint32_t)(a.y >> 7) << 8)
                 | ((uint32_t)(a.z >> 7) << 16) | ((uint32_t)(a.w >> 7) << 24);
    }

    int r = blockIdx.x;
    stage_row(x + (size_t)r * C, rowbuf[0], wave, lane);
    __syncthreads();                   // own-DMA vmcnt drained + barrier
    int cur = 0;

    while (true) {
        const int  rn = r + gridDim.x;
        const bool hn = rn < rows;
        if (hn) stage_row(x + (size_t)rn * C, rowbuf[cur ^ 1], wave, lane);
        // ^ stays in flight through P2 AND P3 (raw barrier skips vmcnt)

        // ---- P2: gather 8, in-lane tree, 16-lane DPP butterfly ----
        const float* rc = rowbuf[cur];
        const float v0 = rc[pidx[0]], v1 = rc[pidx[1]];
        const float v2 = rc[pidx[2]], v3 = rc[pidx[3]];
        const float v4 = rc[pidx[4]], v5 = rc[pidx[5]];
        const float v6 = rc[pidx[6]], v7 = rc[pidx[7]];
        float mx = fmaxf(fmaxf(fmaxf(v0, v1), fmaxf(v2, v3)),
                         fmaxf(fmaxf(v4, v5), fmaxf(v6, v7)));
        float mn = fminf(fminf(fminf(v0, v1), fminf(v2, v3)),
                         fminf(fminf(v4, v5), fminf(v6, v7)));
        mx = fmaxf(mx, dpp_bcast<0xB1>(mx));   // quad_perm [1,0,3,2]  xor1
        mn = fminf(mn, dpp_bcast<0xB1>(mn));
        mx = fmaxf(mx, dpp_bcast<0x4E>(mx));   // quad_perm [2,3,0,1]  xor2
        mn = fminf(mn, dpp_bcast<0x4E>(mn));
        mx = fmaxf(mx, dpp_bcast<0x141>(mx));  // row_half_mirror      xor4
        mn = fminf(mn, dpp_bcast<0x141>(mn));
        mx = fmaxf(mx, dpp_bcast<0x140>(mx));  // row_mirror           xor8
        mn = fminf(mn, dpp_bcast<0x140>(mn));
        if (sl == 0) {
            const float s = fmaxf(mx - mn, 1e-5f) * (1.0f / 15.0f);
            const float b = fminf(fmaxf(rintf(-mn / s), 0.0f), 15.0f);
            sbx[cur][3 * g]     = s;
            sbx[cur][3 * g + 1] = b;
        }

        // ---- publish sb: LDS-only drain + raw barrier (DMA NOT drained) ---
        asm volatile("s_waitcnt lgkmcnt(0)\n\ts_barrier" ::: "memory");

        // ---- P3: linear elementwise quant/dequant, fully coalesced ----
        const float4* rc4 = reinterpret_cast<const float4*>(rc);
        const float*  sbc = sbx[cur];
        float4*       or4 = reinterpret_cast<float4*>(out + (size_t)r * C);
        #pragma unroll
        for (int i = 0; i < VECS; ++i) {
            const float4   v  = rc4[tid + i * BLOCK];   // conflict-free b128
            const uint32_t gp = gpack[i];
            float4 o;
            { const int gi = gp & 31u;
              const float s = sbc[3 * gi], b = sbc[3 * gi + 1];
              o.x = (fminf(fmaxf(rintf(v.x / s) + b, 0.0f), 15.0f) - b) * s; }
            { const int gi = (gp >> 8) & 31u;
              const float s = sbc[3 * gi], b = sbc[3 * gi + 1];
              o.y = (fminf(fmaxf(rintf(v.y / s) + b, 0.0f), 15.0f) - b) * s; }
            { const int gi = (gp >> 16) & 31u;
              const float s = sbc[3 * gi], b = sbc[3 * gi + 1];
              o.z = (fminf(fmaxf(rintf(v.z / s) + b, 0.0f), 15.0f) - b) * s; }
            { const int gi = (gp >> 24) & 31u;
              const float s = sbc[3 * gi], b = sbc[3 * gi + 1];
              o.w = (fminf(fmaxf(rintf(v.w / s) + b, 0.0f), 15.0f) - b) * s; }
            or4[tid + i * BLOCK] = o;
        }

        if (!hn) break;
        r = rn;
        cur ^= 1;
        __syncthreads();   // full drain: DMA(rn) landed; all waves past P3
    }
}

extern "C" void kernel_launch(void* const* d_in, const int* in_sizes, int n_in,
                              void* d_out, int out_size, void* d_ws, size_t ws_size,
                              hipStream_t stream) {
    const float* x   = (const float*)d_in[0];
    const int*   gat = (const int*)d_in[1];   // perm (gather) — P1 partition
    const int*   asn = (const int*)d_in[2];   // inverse perm (assignment)
    float* out = (float*)d_out;

    const int rows = in_sizes[0] / C;            // 16384
    const int nblk = rows < 2048 ? rows : 2048;  // 8 rows/block grid-stride

    tpq_kernel<<<nblk, BLOCK, 0, stream>>>(x, gat, asn, out, rows);
}